// Round 4
// baseline (245.308 us; speedup 1.0000x reference)
//
#include <hip/hip_runtime.h>

// GCNConv(100k nodes, 1M edges, D=128) + two heads (128->64), fp32 in/out.
// R12: kill the gather's dependent-load chain.
//  - xh is PRE-SCALED: xh[i] = fp16(dinv[i]*x[i]); gather = pure row-sum
//    (agg[d] = dv*(sum_edges xh[s] + xh[d])) -- no per-edge weight loads.
//  - Scaling fused into k_node (each block scales its own 128 rows; only
//    needs its own cnt[]), so k_prep shrinks to 17 blocks.
//  - k_gf gather: per node, ONE coalesced 16-wide csr batch load, then
//    shfl-broadcast 4 edges/round, 4 rows (1KB) in flight per wave instr.
// Pipeline: prep(Wf|bf|cursor) -> scatter -> node(sort+dinv+scale-convert)
//           -> gf(gather rowsum + MFMA GEMM).

#define BLOCK 256
#define SB 512           // scatter blocks
#define NB_MAX 784       // max coarse buckets (n<=100352)
#define SLOT 2048        // per-bucket ebuf/csr capacity (avg 1280, max ~1450)
#define CHUNK_MAX 2048   // per-scatter-block edge stash

typedef _Float16 half8 __attribute__((ext_vector_type(8)));
typedef _Float16 half4 __attribute__((ext_vector_type(4)));
typedef float f32x4 __attribute__((ext_vector_type(4)));

// ---------------- prep: Wf fusion (fp16, transposed) | bias + cursor ----------------

__global__ __launch_bounds__(BLOCK) void k_prep(const float* __restrict__ Wg,
                                                const float* __restrict__ Wh,
                                                const float* __restrict__ Wl,
                                                const float* __restrict__ bg,
                                                const float* __restrict__ bh,
                                                const float* __restrict__ bl,
                                                _Float16* __restrict__ WfT,
                                                float* __restrict__ bf,
                                                int* __restrict__ cursor,
                                                int NB) {
    int b = blockIdx.x;
    if (b < 16) {  // Wf = Wg @ [Wh|Wl], stored transposed as fp16: WfT[c][k]
        int r = b * 8 + (threadIdx.x >> 5);
        int c0 = (threadIdx.x & 31) * 4;
        float a0 = 0.f, a1 = 0.f, a2 = 0.f, a3 = 0.f;
        for (int j = 0; j < 128; j++) {
            float wg = Wg[r * 128 + j];
            float4 wc;
            if (c0 < 64) wc = *(const float4*)(Wh + j * 64 + c0);
            else         wc = *(const float4*)(Wl + j * 64 + (c0 - 64));
            a0 += wg * wc.x; a1 += wg * wc.y; a2 += wg * wc.z; a3 += wg * wc.w;
        }
        WfT[(size_t)(c0 + 0) * 128 + r] = (_Float16)a0;
        WfT[(size_t)(c0 + 1) * 128 + r] = (_Float16)a1;
        WfT[(size_t)(c0 + 2) * 128 + r] = (_Float16)a2;
        WfT[(size_t)(c0 + 3) * 128 + r] = (_Float16)a3;
    } else {  // bias fusion + bucket cursor init
        int c = threadIdx.x;
        if (c < 128) {
            float acc = (c < 64) ? bh[c] : bl[c - 64];
            for (int j = 0; j < 128; j++) {
                float wc = (c < 64) ? Wh[j * 64 + c] : Wl[j * 64 + (c - 64)];
                acc += bg[j] * wc;
            }
            bf[c] = acc;
        }
        for (int i = threadIdx.x; i < NB; i += BLOCK) cursor[i] = i * SLOT;
    }
}

// ---------------- scatter: stash chunk in LDS, LDS hist, atomic range reserve ----------------

__global__ __launch_bounds__(BLOCK) void k_scatter(const int* __restrict__ src,
                                                   const int* __restrict__ dst, int E,
                                                   int* __restrict__ cursor,
                                                   int2* __restrict__ ebuf, int NB) {
    __shared__ int2 stash[CHUNK_MAX];
    __shared__ int hist[NB_MAX];
    __shared__ int cur[NB_MAX];
    int blk = blockIdx.x;
    int chunk = (E + SB - 1) / SB;                 // <= CHUNK_MAX
    int e0 = blk * chunk, e1 = min(E, e0 + chunk);
    int m = e1 - e0;

    for (int i = threadIdx.x; i < NB; i += BLOCK) hist[i] = 0;
    __syncthreads();
    for (int i = threadIdx.x; i < m; i += BLOCK) {
        int d = dst[e0 + i], s = src[e0 + i];
        stash[i] = make_int2(d, s);
        atomicAdd(&hist[d >> 7], 1);
    }
    __syncthreads();
    for (int i = threadIdx.x; i < NB; i += BLOCK) {
        int h = hist[i];
        cur[i] = h ? atomicAdd(&cursor[i], h) : 0;  // reserve [base, base+h)
    }
    __syncthreads();
    for (int i = threadIdx.x; i < m; i += BLOCK) {
        int2 p = stash[i];
        int pos = atomicAdd(&cur[p.x >> 7], 1);     // LDS cursor
        ebuf[pos] = p;
    }
}

// ---------------- node: sort -> csr + off2 + dinv, AND scale-convert own rows ----------------

__global__ __launch_bounds__(BLOCK) void k_node(const int2* __restrict__ ebuf,
                                                const int* __restrict__ cursor,
                                                const float* __restrict__ x,
                                                int2* __restrict__ off2,
                                                float* __restrict__ dinv,
                                                int* __restrict__ csr,
                                                _Float16* __restrict__ xh,
                                                int n) {
    __shared__ int cnt[128];
    __shared__ int pre[128];
    __shared__ int cur[128];
    int bkt = blockIdx.x;
    int t = threadIdx.x;
    int node0 = bkt << 7;
    int nn = min(128, n - node0);
    int eb0 = bkt * SLOT;
    int eb1 = cursor[bkt];                          // cursor after scatter = end

    if (t < 128) cnt[t] = 0;
    __syncthreads();
    for (int e = eb0 + t; e < eb1; e += BLOCK)
        atomicAdd(&cnt[ebuf[e].x & 127], 1);
    __syncthreads();
    if (t < 128) pre[t] = cnt[t];
    __syncthreads();
    for (int ofs = 1; ofs < 128; ofs <<= 1) {
        int v = (t < 128 && t >= ofs) ? pre[t - ofs] : 0;
        __syncthreads();
        if (t < 128) pre[t] += v;
        __syncthreads();
    }
    if (t < 128) cur[t] = pre[t] - cnt[t];          // exclusive
    __syncthreads();
    if (t < nn) {
        off2[node0 + t] = make_int2(eb0 + cur[t], eb0 + pre[t]);
        dinv[node0 + t] = rsqrtf((float)(cnt[t] + 1));
    }
    for (int e = eb0 + t; e < eb1; e += BLOCK) {
        int2 p = ebuf[e];
        int pos = atomicAdd(&cur[p.x & 127], 1);    // LDS atomic
        csr[eb0 + pos] = p.y;
    }
    // scale-convert own rows: xh[i] = fp16(dinv_i * x[i])  (cnt[] is stable)
    const float4* xr = (const float4*)(x + (size_t)node0 * 128);
    half4* xw = (half4*)(xh + (size_t)node0 * 128);
    for (int idx = t; idx < nn * 32; idx += BLOCK) {
        int row = idx >> 5;
        float dvL = rsqrtf((float)(cnt[row] + 1));
        float4 v = xr[idx];
        half4 o;
        o.x = (_Float16)(dvL * v.x); o.y = (_Float16)(dvL * v.y);
        o.z = (_Float16)(dvL * v.z); o.w = (_Float16)(dvL * v.w);
        xw[idx] = o;
    }
}

// ---------------- fused gather (pure row-sum) + MFMA final GEMM ----------------
// Block = 256 thr = 4 waves, tile = 64 nodes; wave w owns rows w*16..w*16+16.
// Gather: 4 passes of 4 nodes; group g (lane>>4) owns one node, lane sl
// (lane&15) owns the 16B feature slice. Per node: ONE coalesced 16-wide csr
// batch load, shfl-broadcast 4 edges/round, branch-free masked accumulate.
// agg[d] = dv*(sum_edges xh[s] + xh[d]) with pre-scaled xh. Rows go to
// XOR-swizzled LDS (wave-local, no barrier), then MFMA fp16 GEMM + bias.

__global__ __launch_bounds__(BLOCK) void k_gf(const int2* __restrict__ off2,
                                              const int* __restrict__ csr,
                                              const float* __restrict__ dinv,
                                              const _Float16* __restrict__ xh,
                                              const _Float16* __restrict__ WfT,
                                              const float* __restrict__ bf,
                                              float* __restrict__ out, int n) {
    __shared__ _Float16 lds[64 * 128];              // 16KB tile
    int wave = threadIdx.x >> 6;
    int lane = threadIdx.x & 63;
    int g = lane >> 4;                              // node sub-group / k-block
    int sl = lane & 15;                             // 16B slice / row-in-frag
    int T0 = blockIdx.x * 64;
    int wrow0 = wave * 16;
    int lbase = g << 4;

    // ---- gather phase: 16 nodes per wave, 4 per pass ----
    for (int p = 0; p < 4; p++) {
        int r = wrow0 + p * 4 + g;                  // row in tile, 0..63
        int d = T0 + r;
        int dc = min(d, n - 1);
        int2 oe = off2[dc];                         // broadcast 8B
        float dv = dinv[dc];                        // broadcast 4B
        int beg = oe.x;
        int end = (d < n) ? oe.y : oe.x;
        half8 sv = *(const half8*)(xh + (size_t)dc * 128 + sl * 8);  // self (scaled)
        float acc[8];
#pragma unroll
        for (int k = 0; k < 8; k++) acc[k] = (float)sv[k];

        for (int b0 = beg; b0 < end; b0 += 16) {
            int take = min(16, end - b0);
            int s = 0;
            if (sl < take) s = csr[b0 + sl];        // ONE coalesced 64B batch load
            for (int j = 0; j < take; j += 4) {
                int se0 = __shfl(s, lbase + j);
                int se1 = __shfl(s, lbase + ((j + 1) & 15));
                int se2 = __shfl(s, lbase + ((j + 2) & 15));
                int se3 = __shfl(s, lbase + ((j + 3) & 15));
                float m1 = (j + 1 < take) ? 1.f : 0.f;
                float m2 = (j + 2 < take) ? 1.f : 0.f;
                float m3 = (j + 3 < take) ? 1.f : 0.f;
                half8 v0 = *(const half8*)(xh + (size_t)se0 * 128 + sl * 8);
                half8 v1 = *(const half8*)(xh + (size_t)se1 * 128 + sl * 8);
                half8 v2 = *(const half8*)(xh + (size_t)se2 * 128 + sl * 8);
                half8 v3 = *(const half8*)(xh + (size_t)se3 * 128 + sl * 8);
#pragma unroll
                for (int k = 0; k < 8; k++)
                    acc[k] += (float)v0[k] + m1 * (float)v1[k]
                            + m2 * (float)v2[k] + m3 * (float)v3[k];
            }
        }
        half8 o;
#pragma unroll
        for (int k = 0; k < 8; k++) o[k] = (_Float16)(dv * acc[k]);
        *(half8*)(lds + (size_t)r * 128 + ((sl ^ (r & 7)) * 8)) = o;
    }

    // ---- GEMM phase (wave-local rows; compiler inserts lgkmcnt wait) ----
    int l15 = sl, lk = g;
    half8 a[4];
    {
        int r = wrow0 + l15;
#pragma unroll
        for (int kk = 0; kk < 4; kk++) {
            int ch = (kk * 4 + lk) ^ (l15 & 7);
            a[kk] = *(const half8*)(lds + (size_t)r * 128 + ch * 8);
        }
    }
    f32x4 acc[8];
#pragma unroll
    for (int cf = 0; cf < 8; cf++) acc[cf] = (f32x4){0.f, 0.f, 0.f, 0.f};
#pragma unroll
    for (int kk = 0; kk < 4; kk++) {
#pragma unroll
        for (int cf = 0; cf < 8; cf++) {
            half8 bfr = *(const half8*)(WfT + (size_t)(cf * 16 + l15) * 128 + kk * 32 + lk * 8);
            acc[cf] = __builtin_amdgcn_mfma_f32_16x16x32_f16(a[kk], bfr, acc[cf], 0, 0, 0);
        }
    }
#pragma unroll
    for (int cf = 0; cf < 8; cf++) {
        int c = cf * 16 + l15;
        float bv = bf[c];
        size_t cbase = (c < 64) ? (size_t)c : (size_t)n * 64 + (size_t)(c - 64);
        int r0 = T0 + wrow0 + lk * 4;
#pragma unroll
        for (int j = 0; j < 4; j++) {
            int rr = r0 + j;
            if (rr < n) out[cbase + (size_t)rr * 64] = acc[cf][j] + bv;
        }
    }
}

extern "C" void kernel_launch(void* const* d_in, const int* in_sizes, int n_in,
                              void* d_out, int out_size, void* d_ws, size_t ws_size,
                              hipStream_t stream) {
    const float* x  = (const float*)d_in[0];
    const int*   ei = (const int*)d_in[1];
    const float* Wg = (const float*)d_in[2];
    const float* bg = (const float*)d_in[3];
    const float* Wh = (const float*)d_in[4];
    const float* bh = (const float*)d_in[5];
    const float* Wl = (const float*)d_in[6];
    const float* bl = (const float*)d_in[7];
    float* out = (float*)d_out;

    int n = in_sizes[0] / 128;
    int E = in_sizes[1] / 2;
    const int* src = ei;
    const int* dst = ei + E;
    int NB = (n + 127) >> 7;

#define WS_TAKE(ptr, type, count)                                        \
    ptr = (type*)wsp;                                                    \
    wsp = (char*)(((size_t)(wsp + (size_t)(count) * sizeof(type)) + 255) \
                  & ~(size_t)255)

    char* wsp = (char*)d_ws;
    int*      cursor; WS_TAKE(cursor, int,      NB_MAX);
    int2*     ebuf;   WS_TAKE(ebuf,   int2,     (size_t)NB_MAX * SLOT);
    int2*     off2;   WS_TAKE(off2,   int2,     n);
    float*    dinv;   WS_TAKE(dinv,   float,    n);
    int*      csr;    WS_TAKE(csr,    int,      (size_t)NB_MAX * SLOT);
    _Float16* WfT;    WS_TAKE(WfT,    _Float16, 128 * 128);
    float*    bf;     WS_TAKE(bf,     float,    128);
    _Float16* xh;     WS_TAKE(xh,     _Float16, (size_t)n * 128);

    k_prep<<<17, BLOCK, 0, stream>>>(Wg, Wh, Wl, bg, bh, bl, WfT, bf, cursor, NB);
    k_scatter<<<SB, BLOCK, 0, stream>>>(src, dst, E, cursor, ebuf, NB);
    k_node<<<NB, BLOCK, 0, stream>>>(ebuf, cursor, x, off2, dinv, csr, xh, n);
    k_gf<<<(n + 63) / 64, BLOCK, 0, stream>>>(off2, csr, dinv, xh, WfT, bf, out, n);
}